// Round 1
// baseline (28281.396 us; speedup 1.0000x reference)
//
#include <hip/hip_runtime.h>
#include <math.h>

// ---------------------------------------------------------------------------
// LSTM_DNC: encoder LSTM (T=256, H=512) -> DNC loop (HID_C=759, N=64, W=32, R=4)
// B=64, fp32 everywhere.
//
// Structure:
//  - proj_gemm: chunked precompute of x@Wih_e^T (+b_e) and enc@Wih_c[:, :512]^T (+b_c)
//  - enc_seq:   persistent 256-block kernel, 1 grid barrier per step, h@Whh_e^T
//  - dnc_seq:   persistent 256-block kernel, 2 grid barriers per step:
//               phase A: gates GEMM (K = 759 h + 128 rv) + cell update
//               phase B: DNC memory machinery, one block per batch, state in LDS
// Grid barriers: custom monotonic counter (all 256 blocks co-resident: 256 CUs).
// ---------------------------------------------------------------------------

#define EPSF 1e-6f

__device__ __forceinline__ float sigmoidf_(float x) { return 1.f / (1.f + expf(-x)); }
__device__ __forceinline__ float softplusf_(float x) {
    return (x > 0.f) ? x + log1pf(expf(-x)) : log1pf(expf(x));
}

// Grid barrier: monotonic counter, sense-free. All blocks must be co-resident.
#define GBAR(BARP, BT)                                                                     \
    do {                                                                                   \
        __syncthreads();                                                                   \
        if (threadIdx.x == 0) {                                                            \
            __threadfence();                                                               \
            atomicAdd((BARP), 1);                                                          \
            (BT) += (int)gridDim.x;                                                        \
            while (__hip_atomic_load((BARP), __ATOMIC_RELAXED, __HIP_MEMORY_SCOPE_AGENT) < \
                   (BT)) {                                                                 \
                __builtin_amdgcn_s_sleep(4);                                               \
            }                                                                              \
            __threadfence();                                                               \
        }                                                                                  \
        __syncthreads();                                                                   \
    } while (0)

// Load a 64(batch) x 64(k) fp32 tile into LDS laid out [b][68] (padded rows).
// src must point at element [0][0] of a [64][rowlen] row-major activation array.
__device__ __forceinline__ void load_tile64(const float* __restrict__ src, int rowlen, int kc,
                                            float* lds, int tid) {
#pragma unroll
    for (int i = 0; i < 4; ++i) {
        int e = i * 256 + tid;       // 0..1023 float4 slots
        int b_l = e >> 4;            // 16 float4 per row
        int k4 = (e & 15) << 2;      // 0,4,...,60
        float4 v = *(const float4*)&src[b_l * rowlen + kc + k4];
        *(float4*)&lds[b_l * 68 + k4] = v;
    }
}

// ---------------------------------------------------------------------------
// prep: pad Whh_c [3036][759] -> [3036][768] (zeros), slice Wih_c rv-part -> [3036][128]
// ---------------------------------------------------------------------------
__global__ __launch_bounds__(256) void prep_weights(const float* __restrict__ Whh_c,
                                                    const float* __restrict__ Wih_c,
                                                    float* __restrict__ WhhP,
                                                    float* __restrict__ WrvP) {
    int idx = blockIdx.x * 256 + threadIdx.x;
    const int n1 = 3036 * 768;
    if (idx < n1) {
        int j = idx / 768, k = idx - j * 768;
        WhhP[idx] = (k < 759) ? Whh_c[j * 759 + k] : 0.f;
    }
    if (idx < 3036 * 128) {
        int j = idx >> 7, k = idx & 127;
        WrvP[idx] = Wih_c[j * 640 + 512 + k];
    }
}

// ---------------------------------------------------------------------------
// proj_gemm: OUT[m][j] = bias[j] + sum_{k<512} A[arow(m)][k] * W[j][k]
//   m = tl*64 + b (tl = blockIdx.y tile row block /64)
//   arow(m) = arow_base + (m>>6)*arow_stride_t + (m&63)*arow_stride_b  (row of length arowlen)
// 64x64 tile, 256 threads, 4x4 microtile, K-tiles of 16.
// ---------------------------------------------------------------------------
__global__ __launch_bounds__(256, 2) void proj_gemm(const float* __restrict__ A,
                                                    const float* __restrict__ W,
                                                    const float* __restrict__ bias,
                                                    float* __restrict__ OUT, int Ncols,
                                                    int wstride, int arow_base, int arow_stride_t,
                                                    int arow_stride_b, int arowlen) {
    __shared__ float As[16 * 68];
    __shared__ float Ws[16 * 68];
    const int tid = threadIdx.x;
    const int ntile = blockIdx.x, mtile = blockIdx.y;
    const int tx = tid & 15, ty = tid >> 4;
    const int lr = tid >> 2;          // 0..63: row within tile for loading
    const int lk = (tid & 3) * 4;     // 0,4,8,12: k offset for loading
    const size_t arow =
        (size_t)arow_base + (size_t)mtile * arow_stride_t + (size_t)lr * arow_stride_b;
    const float* aptr = A + arow * arowlen + lk;
    const int wn = ntile * 64 + lr;
    const bool wok = (wn < Ncols);
    const float* wptr = W + (size_t)(wok ? wn : 0) * wstride + lk;
    float acc[4][4] = {};
    for (int kt = 0; kt < 512; kt += 16) {
        float4 av = *(const float4*)(aptr + kt);
        float4 w4l = *(const float4*)(wptr + kt);
        if (!wok) w4l = make_float4(0.f, 0.f, 0.f, 0.f);
        __syncthreads();
        As[(lk + 0) * 68 + lr] = av.x;
        As[(lk + 1) * 68 + lr] = av.y;
        As[(lk + 2) * 68 + lr] = av.z;
        As[(lk + 3) * 68 + lr] = av.w;
        Ws[(lk + 0) * 68 + lr] = w4l.x;
        Ws[(lk + 1) * 68 + lr] = w4l.y;
        Ws[(lk + 2) * 68 + lr] = w4l.z;
        Ws[(lk + 3) * 68 + lr] = w4l.w;
        __syncthreads();
#pragma unroll
        for (int k = 0; k < 16; ++k) {
            float4 a4 = *(const float4*)&As[k * 68 + ty * 4];
            float4 w4 = *(const float4*)&Ws[k * 68 + tx * 4];
            acc[0][0] = fmaf(a4.x, w4.x, acc[0][0]);
            acc[0][1] = fmaf(a4.x, w4.y, acc[0][1]);
            acc[0][2] = fmaf(a4.x, w4.z, acc[0][2]);
            acc[0][3] = fmaf(a4.x, w4.w, acc[0][3]);
            acc[1][0] = fmaf(a4.y, w4.x, acc[1][0]);
            acc[1][1] = fmaf(a4.y, w4.y, acc[1][1]);
            acc[1][2] = fmaf(a4.y, w4.z, acc[1][2]);
            acc[1][3] = fmaf(a4.y, w4.w, acc[1][3]);
            acc[2][0] = fmaf(a4.z, w4.x, acc[2][0]);
            acc[2][1] = fmaf(a4.z, w4.y, acc[2][1]);
            acc[2][2] = fmaf(a4.z, w4.z, acc[2][2]);
            acc[2][3] = fmaf(a4.z, w4.w, acc[2][3]);
            acc[3][0] = fmaf(a4.w, w4.x, acc[3][0]);
            acc[3][1] = fmaf(a4.w, w4.y, acc[3][1]);
            acc[3][2] = fmaf(a4.w, w4.z, acc[3][2]);
            acc[3][3] = fmaf(a4.w, w4.w, acc[3][3]);
        }
    }
    const int col0 = ntile * 64 + tx * 4;
    const int row0 = mtile * 64 + ty * 4;
#pragma unroll
    for (int j = 0; j < 4; ++j) {
        int col = col0 + j;
        if (col < Ncols) {
            float bv = bias[col];
#pragma unroll
            for (int i = 0; i < 4; ++i)
                OUT[(size_t)(row0 + i) * Ncols + col] = acc[i][j] + bv;
        }
    }
}

// ---------------------------------------------------------------------------
// enc_seq: TC encoder steps. 256 blocks x 256 threads. Block bk owns cells 2bk,2bk+1.
// Wave w computes gate w for both cells (rows w*512 + c). c-state in registers.
// ---------------------------------------------------------------------------
__global__ __launch_bounds__(256, 1) void enc_seq(const float* __restrict__ Whh,
                                                  const float* __restrict__ XP,
                                                  float* __restrict__ HE, float* __restrict__ CE,
                                                  float* __restrict__ ENC, int t0, int TC,
                                                  int* bar) {
    __shared__ float lds_h[64 * 68];
    __shared__ float gx[512];  // [gate][cell][b]
    const int tid = threadIdx.x;
    const int bk = blockIdx.x;
    const int lane = tid & 63;
    const int wv = __builtin_amdgcn_readfirstlane(tid >> 6);
    const int c0 = bk * 2;
    const float* w0 = Whh + (size_t)(wv * 512 + c0) * 512;
    const float* w1 = w0 + 512;
    float c_reg = 0.f;
    if (tid < 128) c_reg = CE[(tid & 63) * 512 + c0 + (tid >> 6)];
    int bar_t = 0;
    for (int tl = 0; tl < TC; ++tl) {
        const int t = t0 + tl;
        const int par = t & 1;
        const float* hsrc = HE + par * (64 * 512);
        float acc0 = 0.f, acc1 = 0.f;
        for (int kc = 0; kc < 512; kc += 64) {
            __syncthreads();
            load_tile64(hsrc, 512, kc, lds_h, tid);
            __syncthreads();
            const float* hb = &lds_h[lane * 68];
#pragma unroll
            for (int kk = 0; kk < 64; kk += 4) {
                float4 hv = *(const float4*)&hb[kk];
                float4 wa = *(const float4*)&w0[kc + kk];
                float4 wb = *(const float4*)&w1[kc + kk];
                acc0 = fmaf(hv.x, wa.x, acc0);
                acc0 = fmaf(hv.y, wa.y, acc0);
                acc0 = fmaf(hv.z, wa.z, acc0);
                acc0 = fmaf(hv.w, wa.w, acc0);
                acc1 = fmaf(hv.x, wb.x, acc1);
                acc1 = fmaf(hv.y, wb.y, acc1);
                acc1 = fmaf(hv.z, wb.z, acc1);
                acc1 = fmaf(hv.w, wb.w, acc1);
            }
        }
        {
            const size_t m = (size_t)tl * 64 + lane;
            const float* xp = XP + m * 2048 + (wv * 512 + c0);
            acc0 += xp[0];
            acc1 += xp[1];
        }
        __syncthreads();
        gx[wv * 128 + lane] = acc0;
        gx[wv * 128 + 64 + lane] = acc1;
        __syncthreads();
        if (tid < 128) {
            const int b = tid & 63, cl = tid >> 6;
            float gi = gx[0 + cl * 64 + b];
            float gf = gx[128 + cl * 64 + b];
            float gg = gx[256 + cl * 64 + b];
            float go = gx[384 + cl * 64 + b];
            float cc = sigmoidf_(gf) * c_reg + sigmoidf_(gi) * tanhf(gg);
            float hh = sigmoidf_(go) * tanhf(cc);
            c_reg = cc;
            HE[(par ^ 1) * (64 * 512) + b * 512 + c0 + cl] = hh;
            ENC[((size_t)t * 64 + b) * 512 + c0 + cl] = hh;
        }
        GBAR(bar, bar_t);
    }
    if (tid < 128) CE[(tid & 63) * 512 + c0 + (tid >> 6)] = c_reg;
}

// ---------------------------------------------------------------------------
// dnc_seq: TC DNC steps. 256 blocks x 256 threads.
//  Phase A (blocks 0..252): block owns cells 3bk..3bk+2; wave w = gate w (3 rows).
//    K = 768 (padded h) + 128 (rv). CP holds e_t@Wih_c part (+bias).
//  Phase B (blocks 0..63): batch-b memory machinery; M/L/u/p/ww/wr persist in LDS.
// ---------------------------------------------------------------------------
__global__ __launch_bounds__(256, 1) void dnc_seq(
    const float* __restrict__ WhhP, const float* __restrict__ WrvP, const float* __restrict__ CP,
    float* __restrict__ HC, float* __restrict__ CC, float* __restrict__ Mg,
    float* __restrict__ Ug, float* __restrict__ Pg, float* __restrict__ WWg,
    float* __restrict__ Lg, float* __restrict__ WRg, float* __restrict__ RVg,
    float* __restrict__ OUT, int t0, int TC, int* bar) {
    __shared__ float lds_h[64 * 68];
    __shared__ float gx[768];  // [gate][cell(3)][b]
    __shared__ float M_l[64 * 33];
    __shared__ float L_l[64 * 65];
    __shared__ float act[256];
    __shared__ float wr_l[256];
    __shared__ float u_l[64], p_l[64], ww_l[64], cw_l[64], sM2[64], srt_l[64], asrt_l[64];
    __shared__ int rank_l[64];
    __shared__ float modes_l[12], kss_l[4], scal[4];

    const int tid = threadIdx.x;
    const int bk = blockIdx.x;
    const int lane = tid & 63;
    const int wv = __builtin_amdgcn_readfirstlane(tid >> 6);
    const int b = bk;
    const int c0 = bk * 3;
    const bool gemmb = (bk < 253);
    const bool machb = (bk < 64);

    const float *w0 = WhhP, *w1 = WhhP, *w2 = WhhP, *r0 = WrvP, *r1 = WrvP, *r2 = WrvP;
    if (gemmb) {
        size_t gr = (size_t)(wv * 759 + c0);
        w0 = WhhP + gr * 768;
        w1 = w0 + 768;
        w2 = w1 + 768;
        r0 = WrvP + gr * 128;
        r1 = r0 + 128;
        r2 = r1 + 128;
    }
    float c_reg = 0.f;
    if (gemmb && tid < 192) c_reg = CC[(tid & 63) * 768 + c0 + (tid >> 6)];
    if (machb) {
#pragma unroll
        for (int i = 0; i < 8; ++i) {
            int e = tid + 256 * i;
            M_l[(e >> 5) * 33 + (e & 31)] = Mg[b * 2048 + e];
        }
#pragma unroll
        for (int i = 0; i < 16; ++i) {
            int e = tid + 256 * i;
            L_l[(e >> 6) * 65 + (e & 63)] = Lg[b * 4096 + e];
        }
        wr_l[tid] = WRg[b * 256 + tid];
        if (tid < 64) {
            u_l[tid] = Ug[b * 64 + tid];
            p_l[tid] = Pg[b * 64 + tid];
            ww_l[tid] = WWg[b * 64 + tid];
        }
    }
    int bar_t = 0;
    for (int tl = 0; tl < TC; ++tl) {
        const int t = t0 + tl;
        const int par = t & 1;
        // ------------- phase A: gates GEMM + cell update -------------
        if (gemmb) {
            float acc0 = 0.f, acc1 = 0.f, acc2 = 0.f;
            const float* hsrc = HC + par * (64 * 768);
            for (int kc = 0; kc < 768; kc += 64) {
                __syncthreads();
                load_tile64(hsrc, 768, kc, lds_h, tid);
                __syncthreads();
                const float* hb = &lds_h[lane * 68];
#pragma unroll
                for (int kk = 0; kk < 64; kk += 4) {
                    float4 hv = *(const float4*)&hb[kk];
                    float4 wa = *(const float4*)&w0[kc + kk];
                    float4 wb = *(const float4*)&w1[kc + kk];
                    float4 wc = *(const float4*)&w2[kc + kk];
                    acc0 = fmaf(hv.x, wa.x, acc0);
                    acc0 = fmaf(hv.y, wa.y, acc0);
                    acc0 = fmaf(hv.z, wa.z, acc0);
                    acc0 = fmaf(hv.w, wa.w, acc0);
                    acc1 = fmaf(hv.x, wb.x, acc1);
                    acc1 = fmaf(hv.y, wb.y, acc1);
                    acc1 = fmaf(hv.z, wb.z, acc1);
                    acc1 = fmaf(hv.w, wb.w, acc1);
                    acc2 = fmaf(hv.x, wc.x, acc2);
                    acc2 = fmaf(hv.y, wc.y, acc2);
                    acc2 = fmaf(hv.z, wc.z, acc2);
                    acc2 = fmaf(hv.w, wc.w, acc2);
                }
            }
            for (int kc = 0; kc < 128; kc += 64) {
                __syncthreads();
                load_tile64(RVg, 128, kc, lds_h, tid);
                __syncthreads();
                const float* hb = &lds_h[lane * 68];
#pragma unroll
                for (int kk = 0; kk < 64; kk += 4) {
                    float4 hv = *(const float4*)&hb[kk];
                    float4 wa = *(const float4*)&r0[kc + kk];
                    float4 wb = *(const float4*)&r1[kc + kk];
                    float4 wc = *(const float4*)&r2[kc + kk];
                    acc0 = fmaf(hv.x, wa.x, acc0);
                    acc0 = fmaf(hv.y, wa.y, acc0);
                    acc0 = fmaf(hv.z, wa.z, acc0);
                    acc0 = fmaf(hv.w, wa.w, acc0);
                    acc1 = fmaf(hv.x, wb.x, acc1);
                    acc1 = fmaf(hv.y, wb.y, acc1);
                    acc1 = fmaf(hv.z, wb.z, acc1);
                    acc1 = fmaf(hv.w, wb.w, acc1);
                    acc2 = fmaf(hv.x, wc.x, acc2);
                    acc2 = fmaf(hv.y, wc.y, acc2);
                    acc2 = fmaf(hv.z, wc.z, acc2);
                    acc2 = fmaf(hv.w, wc.w, acc2);
                }
            }
            {
                const size_t m = (size_t)tl * 64 + lane;
                const float* cp = CP + m * 3036 + (wv * 759 + c0);
                acc0 += cp[0];
                acc1 += cp[1];
                acc2 += cp[2];
            }
            __syncthreads();
            gx[wv * 192 + lane] = acc0;
            gx[wv * 192 + 64 + lane] = acc1;
            gx[wv * 192 + 128 + lane] = acc2;
            __syncthreads();
            if (tid < 192) {
                const int bb = tid & 63, cl = tid >> 6;
                float gi = gx[0 + cl * 64 + bb];
                float gf = gx[192 + cl * 64 + bb];
                float gg = gx[384 + cl * 64 + bb];
                float go = gx[576 + cl * 64 + bb];
                float cc = sigmoidf_(gf) * c_reg + sigmoidf_(gi) * tanhf(gg);
                float hh = sigmoidf_(go) * tanhf(cc);
                c_reg = cc;
                const int cg = c0 + cl;
                HC[(par ^ 1) * (64 * 768) + bb * 768 + cg] = hh;
                if (cg < 512) OUT[(size_t)bb * (256 * 512) + (size_t)t * 512 + cg] = hh;
            }
        }
        GBAR(bar, bar_t);
        // ------------- phase B: memory machinery (one block per batch) -------------
        if (machb) {
            const float* hnew = HC + (par ^ 1) * (64 * 768) + b * 768;
            if (tid < 247) {
                float v = hnew[512 + tid];
                float a;
                if (tid < 128) a = tanhf(v);                     // read keys
                else if (tid < 132) a = softplusf_(v);           // read strengths
                else if (tid < 164) a = tanhf(v);                // write key
                else if (tid == 164) a = softplusf_(v);          // write strength
                else if (tid < 197) a = sigmoidf_(v);            // erase
                else if (tid < 229) a = tanhf(v);                // write vec
                else if (tid < 235) a = sigmoidf_(v);            // free gates, alloc g, write g
                else a = v;                                      // read modes (raw)
                act[tid] = a;
            }
            __syncthreads();
            if (tid < 4) {
                float m0 = act[235 + 3 * tid], m1 = act[236 + 3 * tid], m2 = act[237 + 3 * tid];
                float mx = fmaxf(m0, fmaxf(m1, m2));
                float e0 = expf(m0 - mx), e1 = expf(m1 - mx), e2 = expf(m2 - mx);
                float s = e0 + e1 + e2;
                modes_l[3 * tid] = e0 / s;
                modes_l[3 * tid + 1] = e1 / s;
                modes_l[3 * tid + 2] = e2 / s;
                float ks = 0.f;
                for (int w = 0; w < 32; ++w) {
                    float kk = act[tid * 32 + w];
                    ks = fmaf(kk, kk, ks);
                }
                kss_l[tid] = ks;
            }
            if (tid == 64) {
                float s = 0.f;
                for (int w = 0; w < 32; ++w) {
                    float kk = act[132 + w];
                    s = fmaf(kk, kk, s);
                }
                scal[0] = s;
            }
            if (tid < 64) {
                float psi = 1.f;
#pragma unroll
                for (int r = 0; r < 4; ++r) psi *= 1.f - act[229 + r] * wr_l[r * 64 + tid];
                float un = u_l[tid], wwn = ww_l[tid];
                u_l[tid] = (un + wwn - un * wwn) * psi;
                float s2 = 0.f;
                for (int w = 0; w < 32; ++w) {
                    float mm = M_l[tid * 33 + w];
                    s2 = fmaf(mm, mm, s2);
                }
                sM2[tid] = s2;  // pre-write M norms (content write weights)
            }
            __syncthreads();
            if (tid < 64) {  // stable ascending rank of u
                float un = u_l[tid];
                int rk = 0;
                for (int m = 0; m < 64; ++m) {
                    float um = u_l[m];
                    rk += (um < un) || (um == un && m < tid);
                }
                srt_l[rk] = un;
                rank_l[tid] = rk;
            }
            __syncthreads();
            if (tid < 64) {
                // exclusive prefix product over sorted u -> allocation weights
                float v = srt_l[tid];
                float incl = v;
#pragma unroll
                for (int off = 1; off < 64; off <<= 1) {
                    float o = __shfl_up(incl, off);
                    if (tid >= off) incl *= o;
                }
                float excl = __shfl_up(incl, 1);
                if (tid == 0) excl = 1.f;
                asrt_l[tid] = (1.f - v) * excl;
                // content write weights
                float dot = 0.f;
                for (int w = 0; w < 32; ++w) dot = fmaf(act[132 + w], M_l[tid * 33 + w], dot);
                float logit =
                    dot * rsqrtf(sM2[tid] + EPSF) * rsqrtf(scal[0] + EPSF) * act[164];
                float mx = logit;
#pragma unroll
                for (int off = 32; off; off >>= 1) mx = fmaxf(mx, __shfl_xor(mx, off));
                float e = expf(logit - mx);
                float s = e;
#pragma unroll
                for (int off = 32; off; off >>= 1) s += __shfl_xor(s, off);
                cw_l[tid] = e / s;
            }
            __syncthreads();
            if (tid < 64) {
                float a = asrt_l[rank_l[tid]];
                float agv = act[233], wgv = act[234];
                float wn = wgv * (agv * a + (1.f - agv) * cw_l[tid]);
                ww_l[tid] = wn;
                float s = wn;
#pragma unroll
                for (int off = 32; off; off >>= 1) s += __shfl_xor(s, off);
                if (tid == 0) scal[1] = s;
            }
            __syncthreads();
#pragma unroll
            for (int i = 0; i < 8; ++i) {  // M update
                int e = tid + 256 * i;
                int n = e >> 5, w = e & 31;
                float wwn = ww_l[n];
                M_l[n * 33 + w] = M_l[n * 33 + w] * (1.f - wwn * act[165 + w]) + wwn * act[197 + w];
            }
            __syncthreads();
#pragma unroll
            for (int i = 0; i < 16; ++i) {  // L update (uses old p)
                int e = tid + 256 * i;
                int n = e >> 6, m = e & 63;
                float Lv = L_l[n * 65 + m];
                Lv = (1.f - ww_l[n] - ww_l[m]) * Lv + ww_l[n] * p_l[m];
                L_l[n * 65 + m] = (n == m) ? 0.f : Lv;
            }
            __syncthreads();
            if (tid < 64) {
                p_l[tid] = (1.f - scal[1]) * p_l[tid] + ww_l[tid];
                float s2 = 0.f;
                for (int w = 0; w < 32; ++w) {
                    float mm = M_l[tid * 33 + w];
                    s2 = fmaf(mm, mm, s2);
                }
                sM2[tid] = s2;  // post-write M norms (content read weights)
            }
            __syncthreads();
            {
                // read content weights + fw/bw + wr update; wave r handles head r
                const int r = wv;
                const int n = lane;
                float dot = 0.f;
                for (int w = 0; w < 32; ++w) dot = fmaf(act[r * 32 + w], M_l[n * 33 + w], dot);
                float logit =
                    dot * rsqrtf(sM2[n] + EPSF) * rsqrtf(kss_l[r] + EPSF) * act[128 + r];
                float mx = logit;
#pragma unroll
                for (int off = 32; off; off >>= 1) mx = fmaxf(mx, __shfl_xor(mx, off));
                float e = expf(logit - mx);
                float s = e;
#pragma unroll
                for (int off = 32; off; off >>= 1) s += __shfl_xor(s, off);
                float cr = e / s;
                float fw = 0.f, bw = 0.f;
                for (int m = 0; m < 64; ++m) {
                    float wrm = wr_l[r * 64 + m];
                    fw = fmaf(L_l[n * 65 + m], wrm, fw);
                    bw = fmaf(L_l[m * 65 + n], wrm, bw);
                }
                float wrn = modes_l[r * 3] * bw + modes_l[r * 3 + 1] * cr + modes_l[r * 3 + 2] * fw;
                __syncthreads();
                wr_l[tid] = wrn;
            }
            __syncthreads();
            if (tid < 128) {
                const int r = tid >> 5, w = tid & 31;
                float rv = 0.f;
                for (int n = 0; n < 64; ++n) rv = fmaf(wr_l[r * 64 + n], M_l[n * 33 + w], rv);
                RVg[b * 128 + tid] = rv;
            }
        }
        GBAR(bar, bar_t);
    }
    // persist state for next chunk
    if (gemmb && tid < 192) CC[(tid & 63) * 768 + c0 + (tid >> 6)] = c_reg;
    if (machb) {
#pragma unroll
        for (int i = 0; i < 8; ++i) {
            int e = tid + 256 * i;
            Mg[b * 2048 + e] = M_l[(e >> 5) * 33 + (e & 31)];
        }
#pragma unroll
        for (int i = 0; i < 16; ++i) {
            int e = tid + 256 * i;
            Lg[b * 4096 + e] = L_l[(e >> 6) * 65 + (e & 63)];
        }
        WRg[b * 256 + tid] = wr_l[tid];
        if (tid < 64) {
            Ug[b * 64 + tid] = u_l[tid];
            Pg[b * 64 + tid] = p_l[tid];
            WWg[b * 64 + tid] = ww_l[tid];
        }
    }
}

// ---------------------------------------------------------------------------
extern "C" void kernel_launch(void* const* d_in, const int* in_sizes, int n_in, void* d_out,
                              int out_size, void* d_ws, size_t ws_size, hipStream_t stream) {
    const float* x = (const float*)d_in[0];
    const float* Wih_e = (const float*)d_in[1];
    const float* Whh_e = (const float*)d_in[2];
    const float* b_e = (const float*)d_in[3];
    const float* Wih_c = (const float*)d_in[4];
    const float* Whh_c = (const float*)d_in[5];
    const float* b_c = (const float*)d_in[6];
    float* out = (float*)d_out;
    float* ws = (float*)d_ws;

    // timestep-chunk size for the precompute buffers; shrink if ws is small
    int TC = 32;
    while (TC > 2) {
        size_t need = ((size_t)11785216 + (size_t)TC * 325376) * 4;
        if (need <= ws_size) break;
        TC >>= 1;
    }
    const int nch = 256 / TC;

    size_t off = 0;
    float* XP = ws + off;
    off += (size_t)TC * 64 * 2048;  // x@Wih_e^T + b_e, chunk
    float* CPb = ws + off;
    off += (size_t)TC * 64 * 3036;  // enc@Wih_c[:, :512]^T + b_c, chunk
    float* WhhP = ws + off;
    off += (size_t)3036 * 768;  // padded Whh_c
    float* WrvP = ws + off;
    off += (size_t)3036 * 128;  // Wih_c rv slice
    float* ENC = ws + off;
    off += (size_t)256 * 64 * 512;  // encoder outputs (t,b,k)
    size_t zoff = off;
    float* HE = ws + off;
    off += 2 * 64 * 512;
    float* CE = ws + off;
    off += 64 * 512;
    float* HC = ws + off;
    off += 2 * 64 * 768;
    float* CC = ws + off;
    off += 64 * 768;
    float* Mg = ws + off;
    off += 64 * 64 * 32;
    float* Ug = ws + off;
    off += 64 * 64;
    float* Pg = ws + off;
    off += 64 * 64;
    float* WWg = ws + off;
    off += 64 * 64;
    float* Lg = ws + off;
    off += 64 * 64 * 64;
    float* WRg = ws + off;
    off += 64 * 4 * 64;
    float* RVg = ws + off;
    off += 64 * 128;
    int* BAR = (int*)(ws + off);
    off += 512;
    size_t zbytes = (off - zoff) * 4;

    hipMemsetAsync(ws + zoff, 0, zbytes, stream);
    prep_weights<<<dim3((3036 * 768 + 255) / 256), dim3(256), 0, stream>>>(Whh_c, Wih_c, WhhP,
                                                                           WrvP);
    for (int c = 0; c < nch; ++c) {
        proj_gemm<<<dim3(32, TC), dim3(256), 0, stream>>>(x, Wih_e, b_e, XP, 2048, 512, c * TC, 1,
                                                          256, 512);
        enc_seq<<<dim3(256), dim3(256), 0, stream>>>(Whh_e, XP, HE, CE, ENC, c * TC, TC, BAR + c);
    }
    for (int c = 0; c < nch; ++c) {
        proj_gemm<<<dim3(48, TC), dim3(256), 0, stream>>>(ENC, Wih_c, b_c, CPb, 3036, 640,
                                                          c * TC * 64, 64, 1, 512);
        dnc_seq<<<dim3(256), dim3(256), 0, stream>>>(WhhP, WrvP, CPb, HC, CC, Mg, Ug, Pg, WWg, Lg,
                                                     WRg, RVg, out, c * TC, TC, BAR + nch + c);
    }
}

// Round 2
// 21972.923 us; speedup vs baseline: 1.2871x; 1.2871x over previous
//
#include <hip/hip_runtime.h>
#include <math.h>

// ---------------------------------------------------------------------------
// LSTM_DNC round 2: transposed-activation GEMM, no LDS staging.
//  - Activations stored as HX4[k4][b] (float4 over k): lane=batch -> coalesced.
//  - Wave = one cell: 4 gate rows, one K-quarter; weights are wave-uniform
//    (s_load path), partials reduced via small LDS buffer; cell state in regs.
//  - dnc: 256 blocks x 768 threads (12 waves/CU); enc: 256 x 512 (8 waves/CU).
//  - Wcat[3036][896] = [Whh_c | pad | Wih_c rv-part]; machinery writes rv into
//    the k>=768 slots of HX so one K-loop covers h and rv.
// ---------------------------------------------------------------------------

#define EPSF 1e-6f

__device__ __forceinline__ float sigmoidf_(float x) { return 1.f / (1.f + expf(-x)); }
__device__ __forceinline__ float softplusf_(float x) {
    return (x > 0.f) ? x + log1pf(expf(-x)) : log1pf(expf(x));
}

// Grid barrier: monotonic counter. All 256 blocks co-resident (1 per CU).
#define GBAR(BARP, BT)                                                                     \
    do {                                                                                   \
        __syncthreads();                                                                   \
        if (threadIdx.x == 0) {                                                            \
            __threadfence();                                                               \
            atomicAdd((BARP), 1);                                                          \
            (BT) += (int)gridDim.x;                                                        \
            while (__hip_atomic_load((BARP), __ATOMIC_RELAXED, __HIP_MEMORY_SCOPE_AGENT) < \
                   (BT)) {                                                                 \
                __builtin_amdgcn_s_sleep(2);                                               \
            }                                                                              \
            __threadfence();                                                               \
        }                                                                                  \
        __syncthreads();                                                                   \
    } while (0)

// ---------------------------------------------------------------------------
// prep: Wcat[3036][896]: cols 0..758 = Whh_c, 759..767 = 0, 768..895 = Wih_c rv part
// ---------------------------------------------------------------------------
__global__ __launch_bounds__(256) void prep_weights(const float* __restrict__ Whh_c,
                                                    const float* __restrict__ Wih_c,
                                                    float* __restrict__ Wcat) {
    int idx = blockIdx.x * 256 + threadIdx.x;
    if (idx < 3036 * 896) {
        int r = idx / 896, j = idx - r * 896;
        float v;
        if (j < 759) v = Whh_c[r * 759 + j];
        else if (j < 768) v = 0.f;
        else v = Wih_c[r * 640 + 512 + (j - 768)];
        Wcat[idx] = v;
    }
}

// ---------------------------------------------------------------------------
// proj_gemm: OUT^T[j][m] = bias[j] + sum_{k<512} A[arow(m)][k] * W[j][k]
// (transposed output: OUT[(col)*Mrows + m])
// ---------------------------------------------------------------------------
__global__ __launch_bounds__(256, 2) void proj_gemm(const float* __restrict__ A,
                                                    const float* __restrict__ W,
                                                    const float* __restrict__ bias,
                                                    float* __restrict__ OUT, int Ncols,
                                                    int wstride, int arow_base, int arow_stride_t,
                                                    int arow_stride_b, int arowlen, int Mrows) {
    __shared__ float As[16 * 68];
    __shared__ float Ws[16 * 68];
    const int tid = threadIdx.x;
    const int ntile = blockIdx.x, mtile = blockIdx.y;
    const int tx = tid & 15, ty = tid >> 4;
    const int lr = tid >> 2;
    const int lk = (tid & 3) * 4;
    const size_t arow =
        (size_t)arow_base + (size_t)mtile * arow_stride_t + (size_t)lr * arow_stride_b;
    const float* aptr = A + arow * arowlen + lk;
    const int wn = ntile * 64 + lr;
    const bool wok = (wn < Ncols);
    const float* wptr = W + (size_t)(wok ? wn : 0) * wstride + lk;
    float acc[4][4] = {};
    for (int kt = 0; kt < 512; kt += 16) {
        float4 av = *(const float4*)(aptr + kt);
        float4 w4l = *(const float4*)(wptr + kt);
        if (!wok) w4l = make_float4(0.f, 0.f, 0.f, 0.f);
        __syncthreads();
        As[(lk + 0) * 68 + lr] = av.x;
        As[(lk + 1) * 68 + lr] = av.y;
        As[(lk + 2) * 68 + lr] = av.z;
        As[(lk + 3) * 68 + lr] = av.w;
        Ws[(lk + 0) * 68 + lr] = w4l.x;
        Ws[(lk + 1) * 68 + lr] = w4l.y;
        Ws[(lk + 2) * 68 + lr] = w4l.z;
        Ws[(lk + 3) * 68 + lr] = w4l.w;
        __syncthreads();
#pragma unroll
        for (int k = 0; k < 16; ++k) {
            float4 a4 = *(const float4*)&As[k * 68 + ty * 4];
            float4 w4 = *(const float4*)&Ws[k * 68 + tx * 4];
            acc[0][0] = fmaf(a4.x, w4.x, acc[0][0]);
            acc[0][1] = fmaf(a4.x, w4.y, acc[0][1]);
            acc[0][2] = fmaf(a4.x, w4.z, acc[0][2]);
            acc[0][3] = fmaf(a4.x, w4.w, acc[0][3]);
            acc[1][0] = fmaf(a4.y, w4.x, acc[1][0]);
            acc[1][1] = fmaf(a4.y, w4.y, acc[1][1]);
            acc[1][2] = fmaf(a4.y, w4.z, acc[1][2]);
            acc[1][3] = fmaf(a4.y, w4.w, acc[1][3]);
            acc[2][0] = fmaf(a4.z, w4.x, acc[2][0]);
            acc[2][1] = fmaf(a4.z, w4.y, acc[2][1]);
            acc[2][2] = fmaf(a4.z, w4.z, acc[2][2]);
            acc[2][3] = fmaf(a4.z, w4.w, acc[2][3]);
            acc[3][0] = fmaf(a4.w, w4.x, acc[3][0]);
            acc[3][1] = fmaf(a4.w, w4.y, acc[3][1]);
            acc[3][2] = fmaf(a4.w, w4.z, acc[3][2]);
            acc[3][3] = fmaf(a4.w, w4.w, acc[3][3]);
        }
    }
    const int col0 = ntile * 64 + tx * 4;
    const int row0 = mtile * 64 + ty * 4;
#pragma unroll
    for (int j = 0; j < 4; ++j) {
        int col = col0 + j;
        if (col < Ncols) {
            float bv = bias[col];
            float4 st = make_float4(acc[0][j] + bv, acc[1][j] + bv, acc[2][j] + bv,
                                    acc[3][j] + bv);
            *(float4*)&OUT[(size_t)col * Mrows + row0] = st;
        }
    }
}

// ---------------------------------------------------------------------------
// enc_seq: 256 blocks x 512 threads. wave wv: cell = bk + 256*(wv>>2), K-quarter wv&3.
// HXE: transposed h, 2 buffers of 128*64 float4. ENC row-major for the next proj.
// ---------------------------------------------------------------------------
__global__ __launch_bounds__(512, 1) void enc_seq(const float* __restrict__ Whh,
                                                  const float* __restrict__ XPT,
                                                  float* __restrict__ HXE,
                                                  float* __restrict__ CE,
                                                  float* __restrict__ ENC, int M, int t0, int TC,
                                                  int* bar) {
    __shared__ float part[8 * 4 * 64];
    const int tid = threadIdx.x;
    const int bk = blockIdx.x;
    const int lane = tid & 63;
    const int wv = __builtin_amdgcn_readfirstlane(tid >> 6);
    const int q = wv & 3, cidx = wv >> 2;
    const int cell = bk + 256 * cidx;
    const float* __restrict__ w0 = Whh + ((size_t)(0 * 512 + cell)) * 512 + q * 128;
    const float* __restrict__ w1 = Whh + ((size_t)(1 * 512 + cell)) * 512 + q * 128;
    const float* __restrict__ w2 = Whh + ((size_t)(2 * 512 + cell)) * 512 + q * 128;
    const float* __restrict__ w3 = Whh + ((size_t)(3 * 512 + cell)) * 512 + q * 128;
    float c_reg = 0.f;
    if (q == 0) c_reg = CE[cell * 64 + lane];
    int bar_t = 0;
    for (int tl = 0; tl < TC; ++tl) {
        const int t = t0 + tl;
        const int rb = t & 1, wb = rb ^ 1;
        float a0 = 0.f, a1 = 0.f, a2 = 0.f, a3 = 0.f;
        {
            const float4* __restrict__ hx = (const float4*)HXE + (size_t)rb * 8192 + q * 32 * 64;
#pragma unroll 4
            for (int i = 0; i < 32; ++i) {
                float4 hv = hx[i * 64 + lane];
                float4 q0 = *(const float4*)&w0[i * 4];
                float4 q1 = *(const float4*)&w1[i * 4];
                float4 q2 = *(const float4*)&w2[i * 4];
                float4 q3 = *(const float4*)&w3[i * 4];
                a0 = fmaf(hv.x, q0.x, a0); a0 = fmaf(hv.y, q0.y, a0);
                a0 = fmaf(hv.z, q0.z, a0); a0 = fmaf(hv.w, q0.w, a0);
                a1 = fmaf(hv.x, q1.x, a1); a1 = fmaf(hv.y, q1.y, a1);
                a1 = fmaf(hv.z, q1.z, a1); a1 = fmaf(hv.w, q1.w, a1);
                a2 = fmaf(hv.x, q2.x, a2); a2 = fmaf(hv.y, q2.y, a2);
                a2 = fmaf(hv.z, q2.z, a2); a2 = fmaf(hv.w, q2.w, a2);
                a3 = fmaf(hv.x, q3.x, a3); a3 = fmaf(hv.y, q3.y, a3);
                a3 = fmaf(hv.z, q3.z, a3); a3 = fmaf(hv.w, q3.w, a3);
            }
        }
        part[(wv * 4 + 0) * 64 + lane] = a0;
        part[(wv * 4 + 1) * 64 + lane] = a1;
        part[(wv * 4 + 2) * 64 + lane] = a2;
        part[(wv * 4 + 3) * 64 + lane] = a3;
        __syncthreads();
        if (q == 0) {
            float g4[4];
#pragma unroll
            for (int g = 0; g < 4; ++g) {
                g4[g] = part[((cidx * 4 + 0) * 4 + g) * 64 + lane] +
                        part[((cidx * 4 + 1) * 4 + g) * 64 + lane] +
                        part[((cidx * 4 + 2) * 4 + g) * 64 + lane] +
                        part[((cidx * 4 + 3) * 4 + g) * 64 + lane];
            }
            const int m = tl * 64 + lane;
            float gi = g4[0] + XPT[(size_t)(0 * 512 + cell) * M + m];
            float gf = g4[1] + XPT[(size_t)(1 * 512 + cell) * M + m];
            float gg = g4[2] + XPT[(size_t)(2 * 512 + cell) * M + m];
            float go = g4[3] + XPT[(size_t)(3 * 512 + cell) * M + m];
            float cc = sigmoidf_(gf) * c_reg + sigmoidf_(gi) * tanhf(gg);
            float hh = sigmoidf_(go) * tanhf(cc);
            c_reg = cc;
            HXE[(size_t)wb * 32768 + (cell >> 2) * 256 + lane * 4 + (cell & 3)] = hh;
            ENC[((size_t)t * 64 + lane) * 512 + cell] = hh;
        }
        GBAR(bar, bar_t);
    }
    if (q == 0) CE[cell * 64 + lane] = c_reg;
}

// ---------------------------------------------------------------------------
// dnc_seq: 256 blocks x 768 threads. wave wv: cell = bk + 256*(wv>>2) (valid<759),
// K-quarter wv&3 of K=896 (768 h-pad + 128 rv). Machinery: blocks 0..63, batch=bk.
// HX: 2 buffers of 224*64 float4.
// ---------------------------------------------------------------------------
__global__ __launch_bounds__(768, 1) void dnc_seq(
    const float* __restrict__ Wcat, const float* __restrict__ CPT, float* __restrict__ HXf,
    float* __restrict__ CC, float* __restrict__ Mg, float* __restrict__ Ug,
    float* __restrict__ Pg, float* __restrict__ WWg, float* __restrict__ Lg,
    float* __restrict__ WRg, float* __restrict__ OUT, int M, int t0, int TC, int* bar) {
    __shared__ float part[12 * 4 * 64];
    __shared__ float M_l[64 * 33];
    __shared__ float L_l[64 * 65];
    __shared__ float act[256];
    __shared__ float wr_l[256];
    __shared__ float u_l[64], p_l[64], ww_l[64], cw_l[64], sM2[64], srt_l[64], asrt_l[64];
    __shared__ int rank_l[64];
    __shared__ float modes_l[12], kss_l[4], scal[4];

    const int tid = threadIdx.x;
    const int bk = blockIdx.x;
    const int lane = tid & 63;
    const int wv = __builtin_amdgcn_readfirstlane(tid >> 6);
    const int q = wv & 3, cidx = wv >> 2;
    const int cell = bk + 256 * cidx;
    const bool valid = (cell < 759);
    const int b = bk;
    const bool machb = (bk < 64);

    const float* __restrict__ w0 = Wcat + ((size_t)(0 * 759 + (valid ? cell : 0))) * 896 + q * 224;
    const float* __restrict__ w1 = Wcat + ((size_t)(1 * 759 + (valid ? cell : 0))) * 896 + q * 224;
    const float* __restrict__ w2 = Wcat + ((size_t)(2 * 759 + (valid ? cell : 0))) * 896 + q * 224;
    const float* __restrict__ w3 = Wcat + ((size_t)(3 * 759 + (valid ? cell : 0))) * 896 + q * 224;
    float c_reg = 0.f;
    if (q == 0 && valid) c_reg = CC[cell * 64 + lane];

    if (machb) {
#pragma unroll
        for (int i = 0; i < 8; ++i) {
            int e = tid + 256 * i;
            if (tid < 256) M_l[(e >> 5) * 33 + (e & 31)] = Mg[b * 2048 + e];
        }
#pragma unroll
        for (int i = 0; i < 16; ++i) {
            int e = tid + 256 * i;
            if (tid < 256) L_l[(e >> 6) * 65 + (e & 63)] = Lg[b * 4096 + e];
        }
        if (tid < 256) wr_l[tid] = WRg[b * 256 + tid];
        if (tid < 64) {
            u_l[tid] = Ug[b * 64 + tid];
            p_l[tid] = Pg[b * 64 + tid];
            ww_l[tid] = WWg[b * 64 + tid];
        }
    }
    int bar_t = 0;
    for (int tl = 0; tl < TC; ++tl) {
        const int t = t0 + tl;
        const int rb = t & 1, wb = rb ^ 1;
        // ---------------- phase A: gates GEMM ----------------
        float a0 = 0.f, a1 = 0.f, a2 = 0.f, a3 = 0.f;
        if (valid) {
            const float4* __restrict__ hx = (const float4*)HXf + (size_t)rb * 14336 + q * 56 * 64;
#pragma unroll 4
            for (int i = 0; i < 56; ++i) {
                float4 hv = hx[i * 64 + lane];
                float4 q0 = *(const float4*)&w0[i * 4];
                float4 q1 = *(const float4*)&w1[i * 4];
                float4 q2 = *(const float4*)&w2[i * 4];
                float4 q3 = *(const float4*)&w3[i * 4];
                a0 = fmaf(hv.x, q0.x, a0); a0 = fmaf(hv.y, q0.y, a0);
                a0 = fmaf(hv.z, q0.z, a0); a0 = fmaf(hv.w, q0.w, a0);
                a1 = fmaf(hv.x, q1.x, a1); a1 = fmaf(hv.y, q1.y, a1);
                a1 = fmaf(hv.z, q1.z, a1); a1 = fmaf(hv.w, q1.w, a1);
                a2 = fmaf(hv.x, q2.x, a2); a2 = fmaf(hv.y, q2.y, a2);
                a2 = fmaf(hv.z, q2.z, a2); a2 = fmaf(hv.w, q2.w, a2);
                a3 = fmaf(hv.x, q3.x, a3); a3 = fmaf(hv.y, q3.y, a3);
                a3 = fmaf(hv.z, q3.z, a3); a3 = fmaf(hv.w, q3.w, a3);
            }
        }
        part[(wv * 4 + 0) * 64 + lane] = a0;
        part[(wv * 4 + 1) * 64 + lane] = a1;
        part[(wv * 4 + 2) * 64 + lane] = a2;
        part[(wv * 4 + 3) * 64 + lane] = a3;
        __syncthreads();
        if (q == 0 && valid) {
            float g4[4];
#pragma unroll
            for (int g = 0; g < 4; ++g) {
                g4[g] = part[((cidx * 4 + 0) * 4 + g) * 64 + lane] +
                        part[((cidx * 4 + 1) * 4 + g) * 64 + lane] +
                        part[((cidx * 4 + 2) * 4 + g) * 64 + lane] +
                        part[((cidx * 4 + 3) * 4 + g) * 64 + lane];
            }
            const int m = tl * 64 + lane;
            float gi = g4[0] + CPT[(size_t)(0 * 759 + cell) * M + m];
            float gf = g4[1] + CPT[(size_t)(1 * 759 + cell) * M + m];
            float gg = g4[2] + CPT[(size_t)(2 * 759 + cell) * M + m];
            float go = g4[3] + CPT[(size_t)(3 * 759 + cell) * M + m];
            float cc = sigmoidf_(gf) * c_reg + sigmoidf_(gi) * tanhf(gg);
            float hh = sigmoidf_(go) * tanhf(cc);
            c_reg = cc;
            HXf[(size_t)wb * 57344 + (cell >> 2) * 256 + lane * 4 + (cell & 3)] = hh;
            if (cell < 512) OUT[(size_t)lane * 131072 + (size_t)t * 512 + cell] = hh;
        }
        GBAR(bar, bar_t);  // barrier 1: h visible everywhere
        // ---------------- phase B: memory machinery ----------------
        if (machb) {
            const float* __restrict__ HXw = HXf + (size_t)wb * 57344;
            if (tid < 247) {
                float v = HXw[(128 + (tid >> 2)) * 256 + b * 4 + (tid & 3)];
                float a;
                if (tid < 128) a = tanhf(v);
                else if (tid < 132) a = softplusf_(v);
                else if (tid < 164) a = tanhf(v);
                else if (tid == 164) a = softplusf_(v);
                else if (tid < 197) a = sigmoidf_(v);
                else if (tid < 229) a = tanhf(v);
                else if (tid < 235) a = sigmoidf_(v);
                else a = v;
                act[tid] = a;
            }
            __syncthreads();
            if (tid < 4) {
                float m0 = act[235 + 3 * tid], m1 = act[236 + 3 * tid], m2 = act[237 + 3 * tid];
                float mx = fmaxf(m0, fmaxf(m1, m2));
                float e0 = expf(m0 - mx), e1 = expf(m1 - mx), e2 = expf(m2 - mx);
                float s = e0 + e1 + e2;
                modes_l[3 * tid] = e0 / s;
                modes_l[3 * tid + 1] = e1 / s;
                modes_l[3 * tid + 2] = e2 / s;
                float ks = 0.f;
                for (int w = 0; w < 32; ++w) {
                    float kk = act[tid * 32 + w];
                    ks = fmaf(kk, kk, ks);
                }
                kss_l[tid] = ks;
            }
            if (tid == 64) {
                float s = 0.f;
                for (int w = 0; w < 32; ++w) {
                    float kk = act[132 + w];
                    s = fmaf(kk, kk, s);
                }
                scal[0] = s;
            }
            if (tid < 64) {
                float psi = 1.f;
#pragma unroll
                for (int r = 0; r < 4; ++r) psi *= 1.f - act[229 + r] * wr_l[r * 64 + tid];
                float un = u_l[tid], wwn = ww_l[tid];
                u_l[tid] = (un + wwn - un * wwn) * psi;
                float s2 = 0.f;
                for (int w = 0; w < 32; ++w) {
                    float mm = M_l[tid * 33 + w];
                    s2 = fmaf(mm, mm, s2);
                }
                sM2[tid] = s2;
            }
            __syncthreads();
            if (tid < 64) {  // stable ascending rank of u
                float un = u_l[tid];
                int rk = 0;
                for (int m = 0; m < 64; ++m) {
                    float um = u_l[m];
                    rk += (um < un) || (um == un && m < tid);
                }
                srt_l[rk] = un;
                rank_l[tid] = rk;
            }
            __syncthreads();
            if (tid < 64) {
                float v = srt_l[tid];
                float incl = v;
#pragma unroll
                for (int off = 1; off < 64; off <<= 1) {
                    float o = __shfl_up(incl, off);
                    if (tid >= off) incl *= o;
                }
                float excl = __shfl_up(incl, 1);
                if (tid == 0) excl = 1.f;
                asrt_l[tid] = (1.f - v) * excl;
                float dot = 0.f;
                for (int w = 0; w < 32; ++w) dot = fmaf(act[132 + w], M_l[tid * 33 + w], dot);
                float logit = dot * rsqrtf(sM2[tid] + EPSF) * rsqrtf(scal[0] + EPSF) * act[164];
                float mx = logit;
#pragma unroll
                for (int off = 32; off; off >>= 1) mx = fmaxf(mx, __shfl_xor(mx, off));
                float e = expf(logit - mx);
                float s = e;
#pragma unroll
                for (int off = 32; off; off >>= 1) s += __shfl_xor(s, off);
                cw_l[tid] = e / s;
            }
            __syncthreads();
            if (tid < 64) {
                float a = asrt_l[rank_l[tid]];
                float agv = act[233], wgv = act[234];
                float wn = wgv * (agv * a + (1.f - agv) * cw_l[tid]);
                ww_l[tid] = wn;
                float s = wn;
#pragma unroll
                for (int off = 32; off; off >>= 1) s += __shfl_xor(s, off);
                if (tid == 0) scal[1] = s;
            }
            __syncthreads();
            if (tid < 256) {
#pragma unroll
                for (int i = 0; i < 8; ++i) {  // M update
                    int e = tid + 256 * i;
                    int n = e >> 5, w = e & 31;
                    float wwn = ww_l[n];
                    M_l[n * 33 + w] =
                        M_l[n * 33 + w] * (1.f - wwn * act[165 + w]) + wwn * act[197 + w];
                }
#pragma unroll
                for (int i = 0; i < 16; ++i) {  // L update (old p)
                    int e = tid + 256 * i;
                    int n = e >> 6, m = e & 63;
                    float Lv = L_l[n * 65 + m];
                    Lv = (1.f - ww_l[n] - ww_l[m]) * Lv + ww_l[n] * p_l[m];
                    L_l[n * 65 + m] = (n == m) ? 0.f : Lv;
                }
            }
            __syncthreads();
            if (tid < 64) {
                p_l[tid] = (1.f - scal[1]) * p_l[tid] + ww_l[tid];
                float s2 = 0.f;
                for (int w = 0; w < 32; ++w) {
                    float mm = M_l[tid * 33 + w];
                    s2 = fmaf(mm, mm, s2);
                }
                sM2[tid] = s2;
            }
            __syncthreads();
            float wrn = 0.f;
            if (tid < 256) {
                const int r = wv;  // 0..3 for tid<256
                const int n = lane;
                float dot = 0.f;
                for (int w = 0; w < 32; ++w) dot = fmaf(act[r * 32 + w], M_l[n * 33 + w], dot);
                float logit = dot * rsqrtf(sM2[n] + EPSF) * rsqrtf(kss_l[r] + EPSF) * act[128 + r];
                float mx = logit;
#pragma unroll
                for (int off = 32; off; off >>= 1) mx = fmaxf(mx, __shfl_xor(mx, off));
                float e = expf(logit - mx);
                float s = e;
#pragma unroll
                for (int off = 32; off; off >>= 1) s += __shfl_xor(s, off);
                float cr = e / s;
                float fw = 0.f, bw = 0.f;
                for (int m = 0; m < 64; ++m) {
                    float wrm = wr_l[r * 64 + m];
                    fw = fmaf(L_l[n * 65 + m], wrm, fw);
                    bw = fmaf(L_l[m * 65 + n], wrm, bw);
                }
                wrn = modes_l[r * 3] * bw + modes_l[r * 3 + 1] * cr + modes_l[r * 3 + 2] * fw;
            }
            __syncthreads();
            if (tid < 256) wr_l[tid] = wrn;
            __syncthreads();
            if (tid < 128) {
                const int r = tid >> 5, w = tid & 31;
                float rv = 0.f;
                for (int n = 0; n < 64; ++n) rv = fmaf(wr_l[r * 64 + n], M_l[n * 33 + w], rv);
                const int k = 768 + tid;
                HXf[(size_t)wb * 57344 + (k >> 2) * 256 + b * 4 + (k & 3)] = rv;
            }
        }
        GBAR(bar, bar_t);  // barrier 2: rv visible everywhere
    }
    if (q == 0 && valid) CC[cell * 64 + lane] = c_reg;
    if (machb) {
        if (tid < 256) {
#pragma unroll
            for (int i = 0; i < 8; ++i) {
                int e = tid + 256 * i;
                Mg[b * 2048 + e] = M_l[(e >> 5) * 33 + (e & 31)];
            }
#pragma unroll
            for (int i = 0; i < 16; ++i) {
                int e = tid + 256 * i;
                Lg[b * 4096 + e] = L_l[(e >> 6) * 65 + (e & 63)];
            }
            WRg[b * 256 + tid] = wr_l[tid];
        }
        if (tid < 64) {
            Ug[b * 64 + tid] = u_l[tid];
            Pg[b * 64 + tid] = p_l[tid];
            WWg[b * 64 + tid] = ww_l[tid];
        }
    }
}

// ---------------------------------------------------------------------------
extern "C" void kernel_launch(void* const* d_in, const int* in_sizes, int n_in, void* d_out,
                              int out_size, void* d_ws, size_t ws_size, hipStream_t stream) {
    const float* x = (const float*)d_in[0];
    const float* Wih_e = (const float*)d_in[1];
    const float* Whh_e = (const float*)d_in[2];
    const float* b_e = (const float*)d_in[3];
    const float* Wih_c = (const float*)d_in[4];
    const float* Whh_c = (const float*)d_in[5];
    const float* b_c = (const float*)d_in[6];
    float* out = (float*)d_out;
    float* ws = (float*)d_ws;

    int TC = 32;
    while (TC > 2) {
        size_t need = ((size_t)11793000 + (size_t)TC * 325376) * 4;
        if (need <= ws_size) break;
        TC >>= 1;
    }
    const int nch = 256 / TC;
    const int M = TC * 64;

    size_t off = 0;
    float* XPT = ws + off; off += (size_t)2048 * M;   // x@Wih_e^T + b_e, transposed
    float* CPT = ws + off; off += (size_t)3036 * M;   // enc@Wih_c[:,:512]^T + b_c, transposed
    float* Wcat = ws + off; off += (size_t)3036 * 896;
    float* ENC = ws + off; off += (size_t)256 * 64 * 512;  // encoder outputs (t,b,k)
    size_t zoff = off;
    float* HXE = ws + off; off += 2 * 128 * 64 * 4;  // enc h^T, 2 buffers (float4-blocked)
    float* CE = ws + off; off += 512 * 64;
    float* HXf = ws + off; off += 2 * 224 * 64 * 4;  // dnc hx^T, 2 buffers
    float* CC = ws + off; off += 759 * 64;
    float* Mg = ws + off; off += 64 * 2048;
    float* Ug = ws + off; off += 64 * 64;
    float* Pg = ws + off; off += 64 * 64;
    float* WWg = ws + off; off += 64 * 64;
    float* Lg = ws + off; off += 64 * 4096;
    float* WRg = ws + off; off += 64 * 256;
    int* BAR = (int*)(ws + off); off += 512;
    size_t zbytes = (off - zoff) * 4;

    hipMemsetAsync(ws + zoff, 0, zbytes, stream);
    prep_weights<<<dim3((3036 * 896 + 255) / 256), dim3(256), 0, stream>>>(Whh_c, Wih_c, Wcat);
    for (int c = 0; c < nch; ++c) {
        proj_gemm<<<dim3(32, TC), dim3(256), 0, stream>>>(x, Wih_e, b_e, XPT, 2048, 512, c * TC,
                                                          1, 256, 512, M);
        enc_seq<<<dim3(256), dim3(512), 0, stream>>>(Whh_e, XPT, HXE, CE, ENC, M, c * TC, TC,
                                                     BAR + c);
    }
    for (int c = 0; c < nch; ++c) {
        proj_gemm<<<dim3(48, TC), dim3(256), 0, stream>>>(ENC, Wih_c, b_c, CPT, 3036, 640,
                                                          c * TC * 64, 64, 1, 512, M);
        dnc_seq<<<dim3(256), dim3(768), 0, stream>>>(Wcat, CPT, HXf, CC, Mg, Ug, Pg, WWg, Lg, WRg,
                                                     out, M, c * TC, TC, BAR + nch + c);
    }
}

// Round 3
// 16794.498 us; speedup vs baseline: 1.6840x; 1.3083x over previous
//
#include <hip/hip_runtime.h>
#include <math.h>

// ---------------------------------------------------------------------------
// LSTM_DNC round 3: hierarchical grid barrier (16x16 tree) + deeper unroll.
//  - Activations stored as HX4[k4][b] (float4 over k): lane=batch -> coalesced.
//  - Wave = one cell: 4 gate rows, one K-quarter; weights wave-uniform (s_load).
//  - Barrier: per-group counter lines (16 groups of 16 blocks) + root counter;
//    replaces 256 serialized same-line atomics (~25us) with ~2-3us tree.
// ---------------------------------------------------------------------------

#define EPSF 1e-6f

__device__ __forceinline__ float sigmoidf_(float x) { return 1.f / (1.f + expf(-x)); }
__device__ __forceinline__ float softplusf_(float x) {
    return (x > 0.f) ? x + log1pf(expf(-x)) : log1pf(expf(x));
}

// Hierarchical grid barrier: 16 groups x 16 blocks. BARP points at a zeroed
// region of >=544 ints: grp[g] at BARP+g*32 (128B apart), root at BARP+512.
// Monotonic counters, reusable across the dispatch. All blocks co-resident.
#define GBAR(BARP, RND)                                                                    \
    do {                                                                                   \
        __syncthreads();                                                                   \
        if (threadIdx.x == 0) {                                                            \
            (RND) += 1;                                                                    \
            __threadfence();                                                               \
            int* grpc = (BARP) + (((int)blockIdx.x) >> 4) * 32;                            \
            int* rootc = (BARP) + 512;                                                     \
            int old = atomicAdd(grpc, 1);                                                  \
            if (old == (RND)*16 - 1) atomicAdd(rootc, 1);                                  \
            while (__hip_atomic_load(rootc, __ATOMIC_RELAXED, __HIP_MEMORY_SCOPE_AGENT) <  \
                   (RND)*16)                                                               \
                __builtin_amdgcn_s_sleep(1);                                               \
            __threadfence();                                                               \
        }                                                                                  \
        __syncthreads();                                                                   \
    } while (0)

// ---------------------------------------------------------------------------
// prep: Wcat[3036][896]: cols 0..758 = Whh_c, 759..767 = 0, 768..895 = Wih_c rv part
// ---------------------------------------------------------------------------
__global__ __launch_bounds__(256) void prep_weights(const float* __restrict__ Whh_c,
                                                    const float* __restrict__ Wih_c,
                                                    float* __restrict__ Wcat) {
    int idx = blockIdx.x * 256 + threadIdx.x;
    if (idx < 3036 * 896) {
        int r = idx / 896, j = idx - r * 896;
        float v;
        if (j < 759) v = Whh_c[r * 759 + j];
        else if (j < 768) v = 0.f;
        else v = Wih_c[r * 640 + 512 + (j - 768)];
        Wcat[idx] = v;
    }
}

// ---------------------------------------------------------------------------
// proj_gemm: OUT^T[j][m] = bias[j] + sum_{k<512} A[arow(m)][k] * W[j][k]
// (transposed output: OUT[(col)*Mrows + m])
// ---------------------------------------------------------------------------
__global__ __launch_bounds__(256, 2) void proj_gemm(const float* __restrict__ A,
                                                    const float* __restrict__ W,
                                                    const float* __restrict__ bias,
                                                    float* __restrict__ OUT, int Ncols,
                                                    int wstride, int arow_base, int arow_stride_t,
                                                    int arow_stride_b, int arowlen, int Mrows) {
    __shared__ float As[16 * 68];
    __shared__ float Ws[16 * 68];
    const int tid = threadIdx.x;
    const int ntile = blockIdx.x, mtile = blockIdx.y;
    const int tx = tid & 15, ty = tid >> 4;
    const int lr = tid >> 2;
    const int lk = (tid & 3) * 4;
    const size_t arow =
        (size_t)arow_base + (size_t)mtile * arow_stride_t + (size_t)lr * arow_stride_b;
    const float* aptr = A + arow * arowlen + lk;
    const int wn = ntile * 64 + lr;
    const bool wok = (wn < Ncols);
    const float* wptr = W + (size_t)(wok ? wn : 0) * wstride + lk;
    float acc[4][4] = {};
    for (int kt = 0; kt < 512; kt += 16) {
        float4 av = *(const float4*)(aptr + kt);
        float4 w4l = *(const float4*)(wptr + kt);
        if (!wok) w4l = make_float4(0.f, 0.f, 0.f, 0.f);
        __syncthreads();
        As[(lk + 0) * 68 + lr] = av.x;
        As[(lk + 1) * 68 + lr] = av.y;
        As[(lk + 2) * 68 + lr] = av.z;
        As[(lk + 3) * 68 + lr] = av.w;
        Ws[(lk + 0) * 68 + lr] = w4l.x;
        Ws[(lk + 1) * 68 + lr] = w4l.y;
        Ws[(lk + 2) * 68 + lr] = w4l.z;
        Ws[(lk + 3) * 68 + lr] = w4l.w;
        __syncthreads();
#pragma unroll
        for (int k = 0; k < 16; ++k) {
            float4 a4 = *(const float4*)&As[k * 68 + ty * 4];
            float4 w4 = *(const float4*)&Ws[k * 68 + tx * 4];
            acc[0][0] = fmaf(a4.x, w4.x, acc[0][0]);
            acc[0][1] = fmaf(a4.x, w4.y, acc[0][1]);
            acc[0][2] = fmaf(a4.x, w4.z, acc[0][2]);
            acc[0][3] = fmaf(a4.x, w4.w, acc[0][3]);
            acc[1][0] = fmaf(a4.y, w4.x, acc[1][0]);
            acc[1][1] = fmaf(a4.y, w4.y, acc[1][1]);
            acc[1][2] = fmaf(a4.y, w4.z, acc[1][2]);
            acc[1][3] = fmaf(a4.y, w4.w, acc[1][3]);
            acc[2][0] = fmaf(a4.z, w4.x, acc[2][0]);
            acc[2][1] = fmaf(a4.z, w4.y, acc[2][1]);
            acc[2][2] = fmaf(a4.z, w4.z, acc[2][2]);
            acc[2][3] = fmaf(a4.z, w4.w, acc[2][3]);
            acc[3][0] = fmaf(a4.w, w4.x, acc[3][0]);
            acc[3][1] = fmaf(a4.w, w4.y, acc[3][1]);
            acc[3][2] = fmaf(a4.w, w4.z, acc[3][2]);
            acc[3][3] = fmaf(a4.w, w4.w, acc[3][3]);
        }
    }
    const int col0 = ntile * 64 + tx * 4;
    const int row0 = mtile * 64 + ty * 4;
#pragma unroll
    for (int j = 0; j < 4; ++j) {
        int col = col0 + j;
        if (col < Ncols) {
            float bv = bias[col];
            float4 st = make_float4(acc[0][j] + bv, acc[1][j] + bv, acc[2][j] + bv,
                                    acc[3][j] + bv);
            *(float4*)&OUT[(size_t)col * Mrows + row0] = st;
        }
    }
}

// ---------------------------------------------------------------------------
// enc_seq: 256 blocks x 512 threads. wave wv: cell = bk + 256*(wv>>2), K-quarter wv&3.
// HXE: transposed h, 2 buffers of 128*64 float4. ENC row-major for the next proj.
// ---------------------------------------------------------------------------
__global__ __launch_bounds__(512, 1) void enc_seq(const float* __restrict__ Whh,
                                                  const float* __restrict__ XPT,
                                                  float* __restrict__ HXE,
                                                  float* __restrict__ CE,
                                                  float* __restrict__ ENC, int M, int t0, int TC,
                                                  int* bar) {
    __shared__ float part[8 * 4 * 64];
    const int tid = threadIdx.x;
    const int bk = blockIdx.x;
    const int lane = tid & 63;
    const int wv = __builtin_amdgcn_readfirstlane(tid >> 6);
    const int q = wv & 3, cidx = wv >> 2;
    const int cell = bk + 256 * cidx;
    const float* __restrict__ w0 = Whh + ((size_t)(0 * 512 + cell)) * 512 + q * 128;
    const float* __restrict__ w1 = Whh + ((size_t)(1 * 512 + cell)) * 512 + q * 128;
    const float* __restrict__ w2 = Whh + ((size_t)(2 * 512 + cell)) * 512 + q * 128;
    const float* __restrict__ w3 = Whh + ((size_t)(3 * 512 + cell)) * 512 + q * 128;
    float c_reg = 0.f;
    if (q == 0) c_reg = CE[cell * 64 + lane];
    int bar_t = 0;
    for (int tl = 0; tl < TC; ++tl) {
        const int t = t0 + tl;
        const int rb = t & 1, wb = rb ^ 1;
        // prefetch input-projection values (independent of h)
        float x0 = 0.f, x1 = 0.f, x2 = 0.f, x3 = 0.f;
        if (q == 0) {
            const int m = tl * 64 + lane;
            x0 = XPT[(size_t)(0 * 512 + cell) * M + m];
            x1 = XPT[(size_t)(1 * 512 + cell) * M + m];
            x2 = XPT[(size_t)(2 * 512 + cell) * M + m];
            x3 = XPT[(size_t)(3 * 512 + cell) * M + m];
        }
        float a0 = 0.f, a1 = 0.f, a2 = 0.f, a3 = 0.f;
        {
            const float4* __restrict__ hx = (const float4*)HXE + (size_t)rb * 8192 + q * 32 * 64;
#pragma unroll 8
            for (int i = 0; i < 32; ++i) {
                float4 hv = hx[i * 64 + lane];
                float4 q0 = *(const float4*)&w0[i * 4];
                float4 q1 = *(const float4*)&w1[i * 4];
                float4 q2 = *(const float4*)&w2[i * 4];
                float4 q3 = *(const float4*)&w3[i * 4];
                a0 = fmaf(hv.x, q0.x, a0); a0 = fmaf(hv.y, q0.y, a0);
                a0 = fmaf(hv.z, q0.z, a0); a0 = fmaf(hv.w, q0.w, a0);
                a1 = fmaf(hv.x, q1.x, a1); a1 = fmaf(hv.y, q1.y, a1);
                a1 = fmaf(hv.z, q1.z, a1); a1 = fmaf(hv.w, q1.w, a1);
                a2 = fmaf(hv.x, q2.x, a2); a2 = fmaf(hv.y, q2.y, a2);
                a2 = fmaf(hv.z, q2.z, a2); a2 = fmaf(hv.w, q2.w, a2);
                a3 = fmaf(hv.x, q3.x, a3); a3 = fmaf(hv.y, q3.y, a3);
                a3 = fmaf(hv.z, q3.z, a3); a3 = fmaf(hv.w, q3.w, a3);
            }
        }
        part[(wv * 4 + 0) * 64 + lane] = a0;
        part[(wv * 4 + 1) * 64 + lane] = a1;
        part[(wv * 4 + 2) * 64 + lane] = a2;
        part[(wv * 4 + 3) * 64 + lane] = a3;
        __syncthreads();
        if (q == 0) {
            float g4[4];
#pragma unroll
            for (int g = 0; g < 4; ++g) {
                g4[g] = part[((cidx * 4 + 0) * 4 + g) * 64 + lane] +
                        part[((cidx * 4 + 1) * 4 + g) * 64 + lane] +
                        part[((cidx * 4 + 2) * 4 + g) * 64 + lane] +
                        part[((cidx * 4 + 3) * 4 + g) * 64 + lane];
            }
            float gi = g4[0] + x0;
            float gf = g4[1] + x1;
            float gg = g4[2] + x2;
            float go = g4[3] + x3;
            float cc = sigmoidf_(gf) * c_reg + sigmoidf_(gi) * tanhf(gg);
            float hh = sigmoidf_(go) * tanhf(cc);
            c_reg = cc;
            HXE[(size_t)wb * 32768 + (cell >> 2) * 256 + lane * 4 + (cell & 3)] = hh;
            ENC[((size_t)t * 64 + lane) * 512 + cell] = hh;
        }
        GBAR(bar, bar_t);
    }
    if (q == 0) CE[cell * 64 + lane] = c_reg;
}

// ---------------------------------------------------------------------------
// dnc_seq: 256 blocks x 768 threads. wave wv: cell = bk + 256*(wv>>2) (valid<759),
// K-quarter wv&3 of K=896 (768 h-pad + 128 rv). Machinery: blocks 0..63, batch=bk.
// HX: 2 buffers of 224*64 float4.
// ---------------------------------------------------------------------------
__global__ __launch_bounds__(768, 1) void dnc_seq(
    const float* __restrict__ Wcat, const float* __restrict__ CPT, float* __restrict__ HXf,
    float* __restrict__ CC, float* __restrict__ Mg, float* __restrict__ Ug,
    float* __restrict__ Pg, float* __restrict__ WWg, float* __restrict__ Lg,
    float* __restrict__ WRg, float* __restrict__ OUT, int M, int t0, int TC, int* bar) {
    __shared__ float part[12 * 4 * 64];
    __shared__ float M_l[64 * 33];
    __shared__ float L_l[64 * 65];
    __shared__ float act[256];
    __shared__ float wr_l[256];
    __shared__ float u_l[64], p_l[64], ww_l[64], cw_l[64], sM2[64], srt_l[64], asrt_l[64];
    __shared__ int rank_l[64];
    __shared__ float modes_l[12], kss_l[4], scal[4];

    const int tid = threadIdx.x;
    const int bk = blockIdx.x;
    const int lane = tid & 63;
    const int wv = __builtin_amdgcn_readfirstlane(tid >> 6);
    const int q = wv & 3, cidx = wv >> 2;
    const int cell = bk + 256 * cidx;
    const bool valid = (cell < 759);
    const int b = bk;
    const bool machb = (bk < 64);

    const float* __restrict__ w0 = Wcat + ((size_t)(0 * 759 + (valid ? cell : 0))) * 896 + q * 224;
    const float* __restrict__ w1 = Wcat + ((size_t)(1 * 759 + (valid ? cell : 0))) * 896 + q * 224;
    const float* __restrict__ w2 = Wcat + ((size_t)(2 * 759 + (valid ? cell : 0))) * 896 + q * 224;
    const float* __restrict__ w3 = Wcat + ((size_t)(3 * 759 + (valid ? cell : 0))) * 896 + q * 224;
    float c_reg = 0.f;
    if (q == 0 && valid) c_reg = CC[cell * 64 + lane];

    if (machb) {
#pragma unroll
        for (int i = 0; i < 8; ++i) {
            int e = tid + 256 * i;
            if (tid < 256) M_l[(e >> 5) * 33 + (e & 31)] = Mg[b * 2048 + e];
        }
#pragma unroll
        for (int i = 0; i < 16; ++i) {
            int e = tid + 256 * i;
            if (tid < 256) L_l[(e >> 6) * 65 + (e & 63)] = Lg[b * 4096 + e];
        }
        if (tid < 256) wr_l[tid] = WRg[b * 256 + tid];
        if (tid < 64) {
            u_l[tid] = Ug[b * 64 + tid];
            p_l[tid] = Pg[b * 64 + tid];
            ww_l[tid] = WWg[b * 64 + tid];
        }
    }
    int bar_t = 0;
    for (int tl = 0; tl < TC; ++tl) {
        const int t = t0 + tl;
        const int rb = t & 1, wb = rb ^ 1;
        // ---------------- phase A: gates GEMM ----------------
        float a0 = 0.f, a1 = 0.f, a2 = 0.f, a3 = 0.f;
        float p0 = 0.f, p1 = 0.f, p2 = 0.f, p3 = 0.f;
        if (q == 0 && valid) {
            const int m = tl * 64 + lane;
            p0 = CPT[(size_t)(0 * 759 + cell) * M + m];
            p1 = CPT[(size_t)(1 * 759 + cell) * M + m];
            p2 = CPT[(size_t)(2 * 759 + cell) * M + m];
            p3 = CPT[(size_t)(3 * 759 + cell) * M + m];
        }
        if (valid) {
            const float4* __restrict__ hx = (const float4*)HXf + (size_t)rb * 14336 + q * 56 * 64;
#pragma unroll 8
            for (int i = 0; i < 56; ++i) {
                float4 hv = hx[i * 64 + lane];
                float4 q0 = *(const float4*)&w0[i * 4];
                float4 q1 = *(const float4*)&w1[i * 4];
                float4 q2 = *(const float4*)&w2[i * 4];
                float4 q3 = *(const float4*)&w3[i * 4];
                a0 = fmaf(hv.x, q0.x, a0); a0 = fmaf(hv.y, q0.y, a0);
                a0 = fmaf(hv.z, q0.z, a0); a0 = fmaf(hv.w, q0.w, a0);
                a1 = fmaf(hv.x, q1.x, a1); a1 = fmaf(hv.y, q1.y, a1);
                a1 = fmaf(hv.z, q1.z, a1); a1 = fmaf(hv.w, q1.w, a1);
                a2 = fmaf(hv.x, q2.x, a2); a2 = fmaf(hv.y, q2.y, a2);
                a2 = fmaf(hv.z, q2.z, a2); a2 = fmaf(hv.w, q2.w, a2);
                a3 = fmaf(hv.x, q3.x, a3); a3 = fmaf(hv.y, q3.y, a3);
                a3 = fmaf(hv.z, q3.z, a3); a3 = fmaf(hv.w, q3.w, a3);
            }
        }
        part[(wv * 4 + 0) * 64 + lane] = a0;
        part[(wv * 4 + 1) * 64 + lane] = a1;
        part[(wv * 4 + 2) * 64 + lane] = a2;
        part[(wv * 4 + 3) * 64 + lane] = a3;
        __syncthreads();
        if (q == 0 && valid) {
            float g4[4];
#pragma unroll
            for (int g = 0; g < 4; ++g) {
                g4[g] = part[((cidx * 4 + 0) * 4 + g) * 64 + lane] +
                        part[((cidx * 4 + 1) * 4 + g) * 64 + lane] +
                        part[((cidx * 4 + 2) * 4 + g) * 64 + lane] +
                        part[((cidx * 4 + 3) * 4 + g) * 64 + lane];
            }
            float gi = g4[0] + p0;
            float gf = g4[1] + p1;
            float gg = g4[2] + p2;
            float go = g4[3] + p3;
            float cc = sigmoidf_(gf) * c_reg + sigmoidf_(gi) * tanhf(gg);
            float hh = sigmoidf_(go) * tanhf(cc);
            c_reg = cc;
            HXf[(size_t)wb * 57344 + (cell >> 2) * 256 + lane * 4 + (cell & 3)] = hh;
            if (cell < 512) OUT[(size_t)lane * 131072 + (size_t)t * 512 + cell] = hh;
        }
        GBAR(bar, bar_t);  // barrier 1: h visible everywhere
        // ---------------- phase B: memory machinery ----------------
        if (machb) {
            const float* __restrict__ HXw = HXf + (size_t)wb * 57344;
            if (tid < 247) {
                float v = HXw[(128 + (tid >> 2)) * 256 + b * 4 + (tid & 3)];
                float a;
                if (tid < 128) a = tanhf(v);
                else if (tid < 132) a = softplusf_(v);
                else if (tid < 164) a = tanhf(v);
                else if (tid == 164) a = softplusf_(v);
                else if (tid < 197) a = sigmoidf_(v);
                else if (tid < 229) a = tanhf(v);
                else if (tid < 235) a = sigmoidf_(v);
                else a = v;
                act[tid] = a;
            }
            __syncthreads();
            if (tid < 4) {
                float m0 = act[235 + 3 * tid], m1 = act[236 + 3 * tid], m2 = act[237 + 3 * tid];
                float mx = fmaxf(m0, fmaxf(m1, m2));
                float e0 = expf(m0 - mx), e1 = expf(m1 - mx), e2 = expf(m2 - mx);
                float s = e0 + e1 + e2;
                modes_l[3 * tid] = e0 / s;
                modes_l[3 * tid + 1] = e1 / s;
                modes_l[3 * tid + 2] = e2 / s;
                float ks = 0.f;
                for (int w = 0; w < 32; ++w) {
                    float kk = act[tid * 32 + w];
                    ks = fmaf(kk, kk, ks);
                }
                kss_l[tid] = ks;
            }
            if (tid == 64) {
                float s = 0.f;
                for (int w = 0; w < 32; ++w) {
                    float kk = act[132 + w];
                    s = fmaf(kk, kk, s);
                }
                scal[0] = s;
            }
            if (tid < 64) {
                float psi = 1.f;
#pragma unroll
                for (int r = 0; r < 4; ++r) psi *= 1.f - act[229 + r] * wr_l[r * 64 + tid];
                float un = u_l[tid], wwn = ww_l[tid];
                u_l[tid] = (un + wwn - un * wwn) * psi;
                float s2 = 0.f;
                for (int w = 0; w < 32; ++w) {
                    float mm = M_l[tid * 33 + w];
                    s2 = fmaf(mm, mm, s2);
                }
                sM2[tid] = s2;
            }
            __syncthreads();
            if (tid < 64) {  // stable ascending rank of u
                float un = u_l[tid];
                int rk = 0;
                for (int m = 0; m < 64; ++m) {
                    float um = u_l[m];
                    rk += (um < un) || (um == un && m < tid);
                }
                srt_l[rk] = un;
                rank_l[tid] = rk;
            }
            __syncthreads();
            if (tid < 64) {
                float v = srt_l[tid];
                float incl = v;
#pragma unroll
                for (int off = 1; off < 64; off <<= 1) {
                    float o = __shfl_up(incl, off);
                    if (tid >= off) incl *= o;
                }
                float excl = __shfl_up(incl, 1);
                if (tid == 0) excl = 1.f;
                asrt_l[tid] = (1.f - v) * excl;
                float dot = 0.f;
                for (int w = 0; w < 32; ++w) dot = fmaf(act[132 + w], M_l[tid * 33 + w], dot);
                float logit = dot * rsqrtf(sM2[tid] + EPSF) * rsqrtf(scal[0] + EPSF) * act[164];
                float mx = logit;
#pragma unroll
                for (int off = 32; off; off >>= 1) mx = fmaxf(mx, __shfl_xor(mx, off));
                float e = expf(logit - mx);
                float s = e;
#pragma unroll
                for (int off = 32; off; off >>= 1) s += __shfl_xor(s, off);
                cw_l[tid] = e / s;
            }
            __syncthreads();
            if (tid < 64) {
                float a = asrt_l[rank_l[tid]];
                float agv = act[233], wgv = act[234];
                float wn = wgv * (agv * a + (1.f - agv) * cw_l[tid]);
                ww_l[tid] = wn;
                float s = wn;
#pragma unroll
                for (int off = 32; off; off >>= 1) s += __shfl_xor(s, off);
                if (tid == 0) scal[1] = s;
            }
            __syncthreads();
            if (tid < 256) {
#pragma unroll
                for (int i = 0; i < 8; ++i) {  // M update
                    int e = tid + 256 * i;
                    int n = e >> 5, w = e & 31;
                    float wwn = ww_l[n];
                    M_l[n * 33 + w] =
                        M_l[n * 33 + w] * (1.f - wwn * act[165 + w]) + wwn * act[197 + w];
                }
#pragma unroll
                for (int i = 0; i < 16; ++i) {  // L update (old p)
                    int e = tid + 256 * i;
                    int n = e >> 6, m = e & 63;
                    float Lv = L_l[n * 65 + m];
                    Lv = (1.f - ww_l[n] - ww_l[m]) * Lv + ww_l[n] * p_l[m];
                    L_l[n * 65 + m] = (n == m) ? 0.f : Lv;
                }
            }
            __syncthreads();
            if (tid < 64) {
                p_l[tid] = (1.f - scal[1]) * p_l[tid] + ww_l[tid];
                float s2 = 0.f;
                for (int w = 0; w < 32; ++w) {
                    float mm = M_l[tid * 33 + w];
                    s2 = fmaf(mm, mm, s2);
                }
                sM2[tid] = s2;
            }
            __syncthreads();
            float wrn = 0.f;
            if (tid < 256) {
                const int r = wv;  // 0..3 for tid<256
                const int n = lane;
                float dot = 0.f;
                for (int w = 0; w < 32; ++w) dot = fmaf(act[r * 32 + w], M_l[n * 33 + w], dot);
                float logit = dot * rsqrtf(sM2[n] + EPSF) * rsqrtf(kss_l[r] + EPSF) * act[128 + r];
                float mx = logit;
#pragma unroll
                for (int off = 32; off; off >>= 1) mx = fmaxf(mx, __shfl_xor(mx, off));
                float e = expf(logit - mx);
                float s = e;
#pragma unroll
                for (int off = 32; off; off >>= 1) s += __shfl_xor(s, off);
                float cr = e / s;
                float fw = 0.f, bw = 0.f;
                for (int m = 0; m < 64; ++m) {
                    float wrm = wr_l[r * 64 + m];
                    fw = fmaf(L_l[n * 65 + m], wrm, fw);
                    bw = fmaf(L_l[m * 65 + n], wrm, bw);
                }
                wrn = modes_l[r * 3] * bw + modes_l[r * 3 + 1] * cr + modes_l[r * 3 + 2] * fw;
            }
            __syncthreads();
            if (tid < 256) wr_l[tid] = wrn;
            __syncthreads();
            if (tid < 128) {
                const int r = tid >> 5, w = tid & 31;
                float rv = 0.f;
                for (int n = 0; n < 64; ++n) rv = fmaf(wr_l[r * 64 + n], M_l[n * 33 + w], rv);
                const int k = 768 + tid;
                HXf[(size_t)wb * 57344 + (k >> 2) * 256 + b * 4 + (k & 3)] = rv;
            }
        }
        GBAR(bar, bar_t);  // barrier 2: rv visible everywhere
    }
    if (q == 0 && valid) CC[cell * 64 + lane] = c_reg;
    if (machb) {
        if (tid < 256) {
#pragma unroll
            for (int i = 0; i < 8; ++i) {
                int e = tid + 256 * i;
                Mg[b * 2048 + e] = M_l[(e >> 5) * 33 + (e & 31)];
            }
#pragma unroll
            for (int i = 0; i < 16; ++i) {
                int e = tid + 256 * i;
                Lg[b * 4096 + e] = L_l[(e >> 6) * 65 + (e & 63)];
            }
            WRg[b * 256 + tid] = wr_l[tid];
        }
        if (tid < 64) {
            Ug[b * 64 + tid] = u_l[tid];
            Pg[b * 64 + tid] = p_l[tid];
            WWg[b * 64 + tid] = ww_l[tid];
        }
    }
}

// ---------------------------------------------------------------------------
extern "C" void kernel_launch(void* const* d_in, const int* in_sizes, int n_in, void* d_out,
                              int out_size, void* d_ws, size_t ws_size, hipStream_t stream) {
    const float* x = (const float*)d_in[0];
    const float* Wih_e = (const float*)d_in[1];
    const float* Whh_e = (const float*)d_in[2];
    const float* b_e = (const float*)d_in[3];
    const float* Wih_c = (const float*)d_in[4];
    const float* Whh_c = (const float*)d_in[5];
    const float* b_c = (const float*)d_in[6];
    float* out = (float*)d_out;
    float* ws = (float*)d_ws;

    int TC = 32;
    while (TC > 2) {
        size_t need = ((size_t)11808704 + (size_t)TC * 325376) * 4;
        if (need <= ws_size) break;
        TC >>= 1;
    }
    const int nch = 256 / TC;
    const int M = TC * 64;

    size_t off = 0;
    float* XPT = ws + off; off += (size_t)2048 * M;   // x@Wih_e^T + b_e, transposed
    float* CPT = ws + off; off += (size_t)3036 * M;   // enc@Wih_c[:,:512]^T + b_c, transposed
    float* Wcat = ws + off; off += (size_t)3036 * 896;
    float* ENC = ws + off; off += (size_t)256 * 64 * 512;  // encoder outputs (t,b,k)
    size_t zoff = off;
    float* HXE = ws + off; off += 2 * 128 * 64 * 4;  // enc h^T, 2 buffers (float4-blocked)
    float* CE = ws + off; off += 512 * 64;
    float* HXf = ws + off; off += 2 * 224 * 64 * 4;  // dnc hx^T, 2 buffers
    float* CC = ws + off; off += 759 * 64;
    float* Mg = ws + off; off += 64 * 2048;
    float* Ug = ws + off; off += 64 * 64;
    float* Pg = ws + off; off += 64 * 64;
    float* WWg = ws + off; off += 64 * 64;
    float* Lg = ws + off; off += 64 * 4096;
    float* WRg = ws + off; off += 64 * 256;
    int* BAR = (int*)(ws + off); off += 16384;  // 16 chunks x 1024 ints (group lines + root)
    size_t zbytes = (off - zoff) * 4;

    hipMemsetAsync(ws + zoff, 0, zbytes, stream);
    prep_weights<<<dim3((3036 * 896 + 255) / 256), dim3(256), 0, stream>>>(Whh_c, Wih_c, Wcat);
    for (int c = 0; c < nch; ++c) {
        proj_gemm<<<dim3(32, TC), dim3(256), 0, stream>>>(x, Wih_e, b_e, XPT, 2048, 512, c * TC,
                                                          1, 256, 512, M);
        enc_seq<<<dim3(256), dim3(512), 0, stream>>>(Whh_e, XPT, HXE, CE, ENC, M, c * TC, TC,
                                                     BAR + c * 1024);
    }
    for (int c = 0; c < nch; ++c) {
        proj_gemm<<<dim3(48, TC), dim3(256), 0, stream>>>(ENC, Wih_c, b_c, CPT, 3036, 640,
                                                          c * TC * 64, 64, 1, 512, M);
        dnc_seq<<<dim3(256), dim3(768), 0, stream>>>(Wcat, CPT, HXf, CC, Mg, Ug, Pg, WWg, Lg, WRg,
                                                     out, M, c * TC, TC, BAR + (nch + c) * 1024);
    }
}